// Round 2
// baseline (5805.552 us; speedup 1.0000x reference)
//
#include <hip/hip_runtime.h>
#include <cstdint>
#include <cstddef>

#define Bc 8
#define Lc 2048
#define Dc 1152
#define BP 13                                   // positions per block in K1
#define TILES_PER_B ((Lc - 1 + BP - 1) / BP)    // ceil(2047/13) = 158
#define STRIDE 2080                             // padded per-batch stride for boundary arrays
#define G 8                                     // EMA prefetch group depth

// ---------------- Kernel 1: cos_sim -> boundary logit bl ----------------
// One block handles BP consecutive positions t in [t0, t0+BP). For each
// position t: q = Wq . h[t-1], k = Wk . h[t], need |q|^2, |k|^2, q.k.
// 256 threads = 4 waves; wave w handles positions p0=4w..4w+3; each lane owns
// one e-column per iteration (64 lanes x 18 iters = 1152 e's), full-K fp32 dot.
__global__ __launch_bounds__(256) void k1_cos_bl(
    const float* __restrict__ H, const float* __restrict__ Wq,
    const float* __restrict__ Wk, const float* __restrict__ ltemp,
    const float* __restrict__ bbias, float* __restrict__ bl_out)
{
    __shared__ __align__(16) float Hs[(BP + 1) * Dc];  // 14*1152*4 = 64512 B
    int bx = blockIdx.x;
    int batch = bx / TILES_PER_B;
    int tile = bx - batch * TILES_PER_B;
    int t0 = 1 + tile * BP;
    const float* Hb = H + (size_t)batch * Lc * Dc;
    int tid = threadIdx.x;

    // stage rows t0-1 .. t0+BP-1 (row clamp keeps loads in-bounds; clamped
    // rows only feed discarded results)
    {
        const int nf4 = (BP + 1) * (Dc / 4);  // 4032 float4
        float4* dst = (float4*)Hs;
        for (int i = tid; i < nf4; i += 256) {
            int row = i / (Dc / 4);
            int col = i - row * (Dc / 4);
            int grow = t0 - 1 + row;
            if (grow > Lc - 1) grow = Lc - 1;
            dst[i] = ((const float4*)(Hb + (size_t)grow * Dc))[col];
        }
    }
    __syncthreads();

    int el = tid & 63;
    int pg = tid >> 6;
    int p0 = pg * 4;
    // local row for q of position p is p; for k it is p+1. Clamp for the
    // inactive tail slots (p >= BP) so LDS reads stay in-bounds.
    const float* r0 = Hs + min(p0 + 0, BP) * Dc;
    const float* r1 = Hs + min(p0 + 1, BP) * Dc;
    const float* r2 = Hs + min(p0 + 2, BP) * Dc;
    const float* r3 = Hs + min(p0 + 3, BP) * Dc;
    const float* r4 = Hs + min(p0 + 4, BP) * Dc;

    float qq0=0.f,qq1=0.f,qq2=0.f,qq3=0.f;
    float kk0=0.f,kk1=0.f,kk2=0.f,kk3=0.f;
    float qk0=0.f,qk1=0.f,qk2=0.f,qk3=0.f;

    for (int eit = 0; eit < Dc / 64; ++eit) {
        int e = eit * 64 + el;
        const float4* wqr = (const float4*)(Wq + (size_t)e * Dc);
        const float4* wkr = (const float4*)(Wk + (size_t)e * Dc);
        float qa0=0.f,qa1=0.f,qa2=0.f,qa3=0.f;
        float ka0=0.f,ka1=0.f,ka2=0.f,ka3=0.f;
        #pragma unroll 4
        for (int d4 = 0; d4 < Dc / 4; ++d4) {
            float4 wq = wqr[d4];
            float4 wk = wkr[d4];
            float4 h0 = *(const float4*)(r0 + d4 * 4);
            float4 h1 = *(const float4*)(r1 + d4 * 4);
            float4 h2 = *(const float4*)(r2 + d4 * 4);
            float4 h3 = *(const float4*)(r3 + d4 * 4);
            float4 h4 = *(const float4*)(r4 + d4 * 4);
            qa0 += wq.x*h0.x + wq.y*h0.y + wq.z*h0.z + wq.w*h0.w;
            qa1 += wq.x*h1.x + wq.y*h1.y + wq.z*h1.z + wq.w*h1.w;
            qa2 += wq.x*h2.x + wq.y*h2.y + wq.z*h2.z + wq.w*h2.w;
            qa3 += wq.x*h3.x + wq.y*h3.y + wq.z*h3.z + wq.w*h3.w;
            ka0 += wk.x*h1.x + wk.y*h1.y + wk.z*h1.z + wk.w*h1.w;
            ka1 += wk.x*h2.x + wk.y*h2.y + wk.z*h2.z + wk.w*h2.w;
            ka2 += wk.x*h3.x + wk.y*h3.y + wk.z*h3.z + wk.w*h3.w;
            ka3 += wk.x*h4.x + wk.y*h4.y + wk.z*h4.z + wk.w*h4.w;
        }
        qq0 += qa0*qa0; qq1 += qa1*qa1; qq2 += qa2*qa2; qq3 += qa3*qa3;
        kk0 += ka0*ka0; kk1 += ka1*ka1; kk2 += ka2*ka2; kk3 += ka3*ka3;
        qk0 += qa0*ka0; qk1 += qa1*ka1; qk2 += qa2*ka2; qk3 += qa3*ka3;
    }

    // wave-reduce the 12 stats across the 64 e-lanes
    #define WSUM(v) { v += __shfl_xor(v, 32, 64); v += __shfl_xor(v, 16, 64); \
                      v += __shfl_xor(v, 8, 64);  v += __shfl_xor(v, 4, 64);  \
                      v += __shfl_xor(v, 2, 64);  v += __shfl_xor(v, 1, 64); }
    WSUM(qq0) WSUM(qq1) WSUM(qq2) WSUM(qq3)
    WSUM(kk0) WSUM(kk1) WSUM(kk2) WSUM(kk3)
    WSUM(qk0) WSUM(qk1) WSUM(qk2) WSUM(qk3)
    #undef WSUM

    if (el == 0) {
        float T = expf(ltemp[0]);
        T = fminf(fmaxf(T, 0.1f), 10.0f);
        float bias = bbias[0];
        float* blb = bl_out + batch * Lc;
        int t;
        t = t0 + p0 + 0;
        if (p0 + 0 < BP && t < Lc) {
            float den = fmaxf(sqrtf(qq0), 1e-12f) * fmaxf(sqrtf(kk0), 1e-12f);
            blb[t] = (1.0f - qk0 / den) * T + bias;
        }
        t = t0 + p0 + 1;
        if (p0 + 1 < BP && t < Lc) {
            float den = fmaxf(sqrtf(qq1), 1e-12f) * fmaxf(sqrtf(kk1), 1e-12f);
            blb[t] = (1.0f - qk1 / den) * T + bias;
        }
        t = t0 + p0 + 2;
        if (p0 + 2 < BP && t < Lc) {
            float den = fmaxf(sqrtf(qq2), 1e-12f) * fmaxf(sqrtf(kk2), 1e-12f);
            blb[t] = (1.0f - qk2 / den) * T + bias;
        }
        t = t0 + p0 + 3;
        if (p0 + 3 < BP && t < Lc) {
            float den = fmaxf(sqrtf(qq3), 1e-12f) * fmaxf(sqrtf(kk3), 1e-12f);
            blb[t] = (1.0f - qk3 / den) * T + bias;
        }
    }
}

// ---------------- Kernel 2: boundary decision + stable compaction ----------------
// One block per batch. bl[0] is forced to 10. boundary iff bl>0 && mask.
// Mask is read as int32 (harness passes bool/int inputs as int*); note a
// 4-byte read is also nonzero for 4 packed all-true bool bytes, so both
// plausible storage layouts of the all-true mask evaluate true.
// Emits, in t-order: bpos[j] = t_j, pv[j] = clip(sigmoid(2*bl),1e-4,1-1e-4)
// (pv[0]:=1 so the EMA init h=x_0 falls out of the recurrence), nb = count.
// Pads [n, STRIDE) with t=Lc / p=0 so K3's prefetch needs no tail logic.
__global__ __launch_bounds__(256) void k2_boundary(
    const float* __restrict__ bl_in, const int* __restrict__ mask,
    float* __restrict__ pv, int* __restrict__ bpos, int* __restrict__ nb)
{
    int b = blockIdx.x;
    int tid = threadIdx.x;
    const float* blb = bl_in + b * Lc;
    const int* mb = mask + b * Lc;

    float blv[8]; int f[8];
    int t0 = tid * 8;
    int s = 0;
    #pragma unroll
    for (int i = 0; i < 8; ++i) {
        int t = t0 + i;
        float v = (t == 0) ? 10.0f : blb[t];
        blv[i] = v;
        f[i] = (v > 0.0f && mb[t] != 0) ? 1 : 0;
        s += f[i];
    }
    // inclusive scan of per-thread counts over 256 threads (4 waves)
    int lane = tid & 63, wv = tid >> 6;
    int sc = s;
    #pragma unroll
    for (int off = 1; off < 64; off <<= 1) {
        int o = __shfl_up(sc, off, 64);
        if (lane >= off) sc += o;
    }
    __shared__ int wsums[4];
    if (lane == 63) wsums[wv] = sc;
    __syncthreads();
    int woff = 0;
    #pragma unroll
    for (int w = 0; w < 4; ++w) woff += (w < wv) ? wsums[w] : 0;
    int excl = woff + sc - s;
    int total = wsums[0] + wsums[1] + wsums[2] + wsums[3];

    float* pvb = pv + b * STRIDE;
    int* bpb = bpos + b * STRIDE;
    int r = excl;
    #pragma unroll
    for (int i = 0; i < 8; ++i) {
        if (f[i]) {
            int t = t0 + i;
            float p;
            if (t == 0) {
                p = 1.0f;  // makes h = x_0 at j=0 (a[0]=0, b[0]=x_0)
            } else {
                p = 1.0f / (1.0f + expf(-2.0f * blv[i]));   // softmax([-bl,bl])[1]
                p = fminf(fmaxf(p, 1e-4f), 1.0f - 1e-4f);
            }
            bpb[r] = t;
            pvb[r] = p;
            r += 1;
        }
    }
    if (tid == 0) nb[b] = total;
    for (int j = total + tid; j < STRIDE; j += 256) { bpb[j] = Lc; pvb[j] = 0.0f; }
}

// ---------------- Kernel 3: EMA over boundary tokens + span expansion ----------------
// grid (batch, channel-group of 128). Sequential over boundaries; double-
// buffered groups of G=8 prefetched rows hide load latency off the h-chain.
// Position t in [t_j, t_{j+1}) outputs h_j, so each step writes its span.
__global__ __launch_bounds__(128) void k3_ema(
    const float* __restrict__ H, const float* __restrict__ pv,
    const int* __restrict__ bpos, const int* __restrict__ nb,
    float* __restrict__ out)
{
    int b = blockIdx.x;
    int ch = blockIdx.y * 128 + threadIdx.x;
    const float* Hb = H + (size_t)b * Lc * Dc + ch;
    float* Ob = out + (size_t)b * Lc * Dc + ch;
    const float* pvb = pv + b * STRIDE;
    const int* bpb = bpos + b * STRIDE;
    int n = nb[b];
    int ng = (n + G - 1) / G;

    float xA[G], pA[G]; int tA[G + 1];
    #pragma unroll
    for (int i = 0; i < G; ++i) {
        int t = bpb[i];
        tA[i] = t;
        pA[i] = pvb[i];
        xA[i] = (t < Lc) ? Hb[(size_t)t * Dc] : 0.0f;
    }
    tA[G] = bpb[G];

    float h = 0.0f;
    for (int g = 0; g < ng; ++g) {
        int nbase = (g + 1) * G;
        float xB[G], pB[G]; int tB[G + 1];
        #pragma unroll
        for (int i = 0; i < G; ++i) {   // prefetch next group (padding is valid memory)
            int t = bpb[nbase + i];
            tB[i] = t;
            pB[i] = pvb[nbase + i];
            xB[i] = (t < Lc) ? Hb[(size_t)t * Dc] : 0.0f;
        }
        tB[G] = bpb[nbase + G];
        #pragma unroll
        for (int i = 0; i < G; ++i) {
            h = (1.0f - pA[i]) * h + pA[i] * xA[i];   // padding: p=0 keeps h
            int te = tA[i + 1];
            for (int tt = tA[i]; tt < te; ++tt) Ob[(size_t)tt * Dc] = h;
        }
        #pragma unroll
        for (int i = 0; i < G; ++i) { xA[i] = xB[i]; pA[i] = pB[i]; tA[i] = tB[i]; }
        tA[G] = tB[G];
    }
}

extern "C" void kernel_launch(void* const* d_in, const int* in_sizes, int n_in,
                              void* d_out, int out_size, void* d_ws, size_t ws_size,
                              hipStream_t stream)
{
    const float* H  = (const float*)d_in[0];
    const float* Wq = (const float*)d_in[1];
    const float* Wk = (const float*)d_in[2];
    const float* lt = (const float*)d_in[3];
    const float* bb = (const float*)d_in[4];
    const int* mask = (const int*)d_in[5];
    float* out = (float*)d_out;

    char* ws = (char*)d_ws;
    float* bl   = (float*)ws;                                     // 8*2048 floats
    float* pv   = (float*)(ws + (size_t)Bc * Lc * 4);             // 8*2080 floats
    int*   bpos = (int*)  (ws + (size_t)Bc * Lc * 4 + (size_t)Bc * STRIDE * 4);
    int*   nbp  = (int*)  (ws + (size_t)Bc * Lc * 4 + 2ull * Bc * STRIDE * 4);

    hipLaunchKernelGGL(k1_cos_bl, dim3(Bc * TILES_PER_B), dim3(256), 0, stream,
                       H, Wq, Wk, lt, bb, bl);
    hipLaunchKernelGGL(k2_boundary, dim3(Bc), dim3(256), 0, stream,
                       bl, mask, pv, bpos, nbp);
    hipLaunchKernelGGL(k3_ema, dim3(Bc, 9), dim3(128), 0, stream,
                       H, pv, bpos, nbp, out);
}